// Round 5
// baseline (222.187 us; speedup 1.0000x reference)
//
#include <hip/hip_runtime.h>
#include <hip/hip_bf16.h>

// Problem constants (match reference)
#define CUTOFF_C    12.0f
#define CUTOFF_SR_C 2.0f
#define CUTOFF_SQ_C 144.0f
#define KEHALF_C    7.199822675975274f

// ---- bucketed-path parameters ----
#define BCHUNK      16384   // power of 2: chunk = i >> 14, local = i & 16383
#define BNCHUNK     7       // 7 * 16384 = 114688 >= 100000
#define BLK_F       512     // fused producer block
#define BLK_S       512     // scatter block (64 KB LDS -> 2 blocks/CU)

// ---- legacy fallback parameters (round-4 path) ----
#define CHUNK    16000
#define NCHUNK   7
#define BLOCK_SC 512
#define S_FULL   72

__device__ __forceinline__ float edge_energy(float d, float qi, float qj,
                                             float di, float dj) {
    float inv_d   = __frcp_rn(d);
    float dsh     = __fsqrt_rn(fmaf(d, d, 1.0f));
    float inv_dsh = __frcp_rn(dsh);

    // poly6 switch on [0, CUTOFF_SR): 1 - 10x^3 + 15x^4 - 6x^5
    float x  = d * (1.0f / CUTOFF_SR_C);
    float x3 = x * x * x;
    float sw = fmaf(x3, fmaf(x, fmaf(x, -6.0f, 15.0f), -10.0f), 1.0f);
    float sw_off = (d < CUTOFF_SR_C) ? sw : 0.0f;

    float Eoq = inv_d   + fmaf(d,   (1.0f / CUTOFF_SQ_C), -(2.0f / CUTOFF_C));
    float Esq = inv_dsh + fmaf(dsh, (1.0f / CUTOFF_SQ_C), -(2.0f / CUTOFF_C));
    float Eq  = (KEHALF_C * qi * qj) * fmaf(sw_off, Esq - Eoq, Eoq);

    float Eod = inv_d * inv_d * inv_d;
    float Esd = inv_dsh * inv_dsh * inv_dsh;
    float Ed  = (KEHALF_C * di * dj) * fmaf(sw_off, Esd - Eod, Eod);

    return Eq + Ed;
}

// Pack {q, dip} -> float2: one 8B gather per endpoint.
__global__ __launch_bounds__(256) void pc_pack_qd(
    const float* __restrict__ q,
    const float* __restrict__ dip,
    float2*      __restrict__ qd,
    int n_atoms)
{
    int a = blockIdx.x * 256 + threadIdx.x;
    if (a < n_atoms) qd[a] = make_float2(q[a], dip[a]);
}

// ============ bucketed path ============

// Fused compute + bucketize. Block b appends (local, E) items into its 7
// private fixed-capacity slabs; position from an LDS counter. Overflow
// (statistically ~never) goes through a global-atomic per-atom array so
// correctness never depends on CAP.
__global__ __launch_bounds__(BLK_F) void pc_fused_bucket(
    const float2* __restrict__ qd,
    const float*  __restrict__ dist,
    const int*    __restrict__ idx_i,
    const int*    __restrict__ idx_j,
    uint2*        __restrict__ slabs,    // [NB][BNCHUNK][CAP]
    int*          __restrict__ counts,   // [NB][BNCHUNK]
    float*        __restrict__ overflow, // [n_atoms], pre-zeroed
    int n_edges, int n4, int gps, int CAP, int NB)
{
    __shared__ int cnt[BNCHUNK];
    if (threadIdx.x < BNCHUNK) cnt[threadIdx.x] = 0;
    __syncthreads();

    const int b  = blockIdx.x;
    const int g0 = b * gps;
    const int g1 = min(g0 + gps, n4);
    uint2* myslab = slabs + (size_t)b * BNCHUNK * CAP;

    const float4* dist4 = (const float4*)dist;
    const int4*   idxi4 = (const int4*)idx_i;
    const int4*   idxj4 = (const int4*)idx_j;

    for (int g = g0 + (int)threadIdx.x; g < g1; g += BLK_F) {
        float4 d4 = dist4[g];
        int4   i4 = idxi4[g];
        int4   j4 = idxj4[g];
        #pragma unroll
        for (int k = 0; k < 4; ++k) {
            float d = (k == 0) ? d4.x : (k == 1) ? d4.y : (k == 2) ? d4.z : d4.w;
            int   i = (k == 0) ? i4.x : (k == 1) ? i4.y : (k == 2) ? i4.z : i4.w;
            int   j = (k == 0) ? j4.x : (k == 1) ? j4.y : (k == 2) ? j4.z : j4.w;
            if (d <= CUTOFF_C) {
                float2 qdi = qd[i];
                float2 qdj = qd[j];
                float  E   = edge_energy(d, qdi.x, qdj.x, qdi.y, qdj.y);
                int    c   = i >> 14;
                int    p   = atomicAdd(&cnt[c], 1);
                if (p < CAP)
                    myslab[c * CAP + p] =
                        make_uint2((unsigned)(i & (BCHUNK - 1)),
                                   __float_as_uint(E));
                else
                    atomicAdd(&overflow[i], E);   // safety valve
            }
        }
    }

    // scalar tail (n_edges % 4), last block only
    if (b == NB - 1) {
        for (int e = (n4 << 2) + (int)threadIdx.x; e < n_edges; e += BLK_F) {
            float d = dist[e];
            if (d <= CUTOFF_C) {
                int i = idx_i[e], jj = idx_j[e];
                float2 qdi = qd[i];
                float2 qdj = qd[jj];
                float  E   = edge_energy(d, qdi.x, qdj.x, qdi.y, qdj.y);
                int    c   = i >> 14;
                int    p   = atomicAdd(&cnt[c], 1);
                if (p < CAP)
                    myslab[c * CAP + p] =
                        make_uint2((unsigned)(i & (BCHUNK - 1)),
                                   __float_as_uint(E));
                else
                    atomicAdd(&overflow[i], E);
            }
        }
    }

    __syncthreads();
    if (threadIdx.x < BNCHUNK) counts[b * BNCHUNK + threadIdx.x] = cnt[threadIdx.x];
}

// Scatter: block (c, t) drains bucket c of producers [t*NB/S2, (t+1)*NB/S2).
// Every item read is useful (no filtering); ds_add into 64 KB LDS chunk;
// flush with plain coalesced stores into partial row t.
__global__ __launch_bounds__(BLK_S) void pc_scatter_bkt(
    const uint2* __restrict__ slabs,
    const int*   __restrict__ counts,
    float*       __restrict__ partial,   // [S2][n_atoms]
    int NB, int CAP, int S2, int n_atoms)
{
    __shared__ float acc[BCHUNK];        // 65536 B
    const int c = blockIdx.x % BNCHUNK;
    const int t = blockIdx.x / BNCHUNK;

    for (int i = threadIdx.x; i < BCHUNK; i += BLK_S) acc[i] = 0.0f;
    __syncthreads();

    const int per = NB / S2;
    const int b0 = t * per, b1 = b0 + per;
    for (int b = b0; b < b1; ++b) {
        int n = counts[b * BNCHUNK + c];
        if (n > CAP) n = CAP;            // overflow items went to the global array
        const uint2* base = slabs + (size_t)(b * BNCHUNK + c) * CAP;
        for (int k = threadIdx.x; k < n; k += BLK_S) {
            uint2 it = base[k];
            atomicAdd(&acc[it.x], __uint_as_float(it.y));
        }
    }

    __syncthreads();
    const int abase = c * BCHUNK;
    const int lim   = min(BCHUNK, n_atoms - abase);
    float* row = partial + (size_t)t * n_atoms + abase;
    for (int i = threadIdx.x; i < lim; i += BLK_S) row[i] = acc[i];
}

// Reduce: out[a] = overflow[a] + sum_t partial[t][a].
__global__ __launch_bounds__(256) void pc_reduce_ovf(
    const float* __restrict__ partial,
    const float* __restrict__ overflow,
    float*       __restrict__ out,
    int n_atoms, int S)
{
    __shared__ float sh[256];
    int a0   = blockIdx.x * 64;
    int lane = threadIdx.x & 63;
    int w    = threadIdx.x >> 6;
    int a    = a0 + lane;

    float v0 = 0.0f, v1 = 0.0f;
    if (a < n_atoms) {
        int per = S >> 2;                // S % 4 == 0
        const float* p = partial + a;
        int s = w * per, send = s + per;
        for (; s + 2 <= send; s += 2) {
            v0 += p[(size_t)(s + 0) * n_atoms];
            v1 += p[(size_t)(s + 1) * n_atoms];
        }
        for (; s < send; ++s) v0 += p[(size_t)s * n_atoms];
    }
    sh[threadIdx.x] = v0 + v1;
    __syncthreads();
    if (w == 0 && a < n_atoms)
        out[a] = (sh[lane] + sh[64 + lane]) + (sh[128 + lane] + sh[192 + lane])
                 + overflow[a];
}

// ============ legacy fallback path (round-4) ============

__global__ __launch_bounds__(256) void pc_compute_E(
    const float2* __restrict__ qd,
    const float*  __restrict__ dist,
    const int*    __restrict__ idx_i,
    const int*    __restrict__ idx_j,
    float*        __restrict__ E,
    int n_edges, int n4)
{
    int t = blockIdx.x * 256 + threadIdx.x;
    if (t < n4) {
        float4 d4 = ((const float4*)dist)[t];
        int4   i4 = ((const int4*)idx_i)[t];
        int4   j4 = ((const int4*)idx_j)[t];
        float4 e4;
        #pragma unroll
        for (int k = 0; k < 4; ++k) {
            float d = (k == 0) ? d4.x : (k == 1) ? d4.y : (k == 2) ? d4.z : d4.w;
            int   i = (k == 0) ? i4.x : (k == 1) ? i4.y : (k == 2) ? i4.z : i4.w;
            int   j = (k == 0) ? j4.x : (k == 1) ? j4.y : (k == 2) ? j4.z : j4.w;
            float2 qdi = qd[i];
            float2 qdj = qd[j];
            float e = (d <= CUTOFF_C)
                        ? edge_energy(d, qdi.x, qdj.x, qdi.y, qdj.y) : 0.0f;
            if (k == 0) e4.x = e; else if (k == 1) e4.y = e;
            else if (k == 2) e4.z = e; else e4.w = e;
        }
        ((float4*)E)[t] = e4;
    }
    int total = gridDim.x * 256;
    for (int e = (n4 << 2) + t; e < n_edges; e += total) {
        float d = dist[e];
        float2 qdi = qd[idx_i[e]];
        float2 qdj = qd[idx_j[e]];
        E[e] = (d <= CUTOFF_C)
                 ? edge_energy(d, qdi.x, qdj.x, qdi.y, qdj.y) : 0.0f;
    }
}

__global__ __launch_bounds__(BLOCK_SC) void pc_scatter(
    const int*   __restrict__ idx_i,
    const float* __restrict__ E,
    float*       __restrict__ partial,
    int n_edges, int n4, int S, int gps, int n_atoms)
{
    __shared__ float acc[CHUNK];
    int c = blockIdx.x % NCHUNK;
    int s = blockIdx.x / NCHUNK;
    const int base = c * CHUNK;

    for (int i = threadIdx.x; i < CHUNK; i += BLOCK_SC) acc[i] = 0.0f;
    __syncthreads();

    const int g0 = s * gps;
    const int g1 = min(g0 + gps, n4);
    const int4*   idxi4 = (const int4*)idx_i;
    const float4* E4p   = (const float4*)E;

    for (int g = g0 + (int)threadIdx.x; g < g1; g += BLOCK_SC) {
        int4   i4 = idxi4[g];
        float4 e4 = E4p[g];
        #pragma unroll
        for (int k = 0; k < 4; ++k) {
            int   i = (k == 0) ? i4.x : (k == 1) ? i4.y : (k == 2) ? i4.z : i4.w;
            float e = (k == 0) ? e4.x : (k == 1) ? e4.y : (k == 2) ? e4.z : e4.w;
            unsigned local = (unsigned)(i - base);
            if (local < (unsigned)CHUNK && e != 0.0f)
                atomicAdd(&acc[local], e);
        }
    }
    if (s == S - 1) {
        for (int e = (n4 << 2) + (int)threadIdx.x; e < n_edges; e += BLOCK_SC) {
            unsigned local = (unsigned)(idx_i[e] - base);
            float ev = E[e];
            if (local < (unsigned)CHUNK && ev != 0.0f)
                atomicAdd(&acc[local], ev);
        }
    }
    __syncthreads();
    int lim = min(CHUNK, n_atoms - base);
    float* row = partial + (size_t)s * n_atoms + base;
    for (int i = threadIdx.x; i < lim; i += BLOCK_SC) row[i] = acc[i];
}

__global__ __launch_bounds__(256) void pc_reduce(
    const float* __restrict__ partial,
    float*       __restrict__ out,
    int n_atoms, int S)
{
    __shared__ float sh[256];
    int a0   = blockIdx.x * 64;
    int lane = threadIdx.x & 63;
    int w    = threadIdx.x >> 6;
    int a    = a0 + lane;
    float v0 = 0.0f, v1 = 0.0f;
    if (a < n_atoms) {
        int per = S >> 2;
        const float* p = partial + a;
        int s = w * per, send = s + per;
        for (; s + 2 <= send; s += 2) {
            v0 += p[(size_t)(s + 0) * n_atoms];
            v1 += p[(size_t)(s + 1) * n_atoms];
        }
        for (; s < send; ++s) v0 += p[(size_t)s * n_atoms];
    }
    sh[threadIdx.x] = v0 + v1;
    __syncthreads();
    if (w == 0 && a < n_atoms)
        out[a] = (sh[lane] + sh[64 + lane]) + (sh[128 + lane] + sh[192 + lane]);
}

__global__ __launch_bounds__(256) void pc_dipole_edges_atomic(
    const float* __restrict__ q,
    const float* __restrict__ dip,
    const float* __restrict__ dist,
    const int*   __restrict__ idx_i,
    const int*   __restrict__ idx_j,
    float*       __restrict__ out,
    int n_edges)
{
    int t = blockIdx.x * blockDim.x + threadIdx.x;
    const int stride = gridDim.x * blockDim.x;
    for (int e = t; e < n_edges; e += stride) {
        float d = dist[e];
        if (d > CUTOFF_C) continue;
        int i = idx_i[e], j = idx_j[e];
        atomicAdd(&out[i], edge_energy(d, q[i], q[j], dip[i], dip[j]));
    }
}

extern "C" void kernel_launch(void* const* d_in, const int* in_sizes, int n_in,
                              void* d_out, int out_size, void* d_ws, size_t ws_size,
                              hipStream_t stream) {
    const float* q     = (const float*)d_in[0];
    const float* dip   = (const float*)d_in[1];
    const float* dist  = (const float*)d_in[2];
    const int*   idx_i = (const int*)d_in[3];
    const int*   idx_j = (const int*)d_in[4];
    float*       out   = (float*)d_out;

    int n_edges = in_sizes[2];
    int n_atoms = out_size;
    int n4      = n_edges >> 2;

    // ---- try the bucketed path (largest config that fits ws) ----
    const int cfgNB[3] = {768, 256, 128};
    const int cfgS2[3] = { 64,  32,  16};

    if (n_atoms <= BNCHUNK * BCHUNK && n_atoms > 0) {
        for (int ci = 0; ci < 3; ++ci) {
            int NB = cfgNB[ci], S2 = cfgS2[ci];
            int gps = (n4 + NB - 1) / NB;
            long   epb  = (long)gps * 4;
            double p    = (double)BCHUNK / (double)n_atoms;
            if (p > 1.0) p = 1.0;
            double mean = (double)epb * p;
            double sig  = sqrt((double)epb * p * (1.0 - p));
            int CAP = (int)(mean + 10.0 * sig + 64.0);

            size_t off = 0;
            auto alloc = [&](size_t bytes) {
                size_t o = off;
                off = (off + bytes + 255) & ~(size_t)255;
                return o;
            };
            size_t qd_off   = alloc((size_t)n_atoms * sizeof(float2));
            size_t ovf_off  = alloc((size_t)n_atoms * sizeof(float));
            size_t cnt_off  = alloc((size_t)NB * BNCHUNK * sizeof(int));
            size_t slab_off = alloc((size_t)NB * BNCHUNK * CAP * sizeof(uint2));
            size_t part_off = alloc((size_t)S2 * n_atoms * sizeof(float));
            if (off > ws_size) continue;

            float2* qd      = (float2*)((char*)d_ws + qd_off);
            float*  ovf     = (float*) ((char*)d_ws + ovf_off);
            int*    counts  = (int*)   ((char*)d_ws + cnt_off);
            uint2*  slabs   = (uint2*) ((char*)d_ws + slab_off);
            float*  partial = (float*) ((char*)d_ws + part_off);

            pc_pack_qd<<<(n_atoms + 255) / 256, 256, 0, stream>>>(q, dip, qd,
                                                                  n_atoms);
            hipMemsetAsync(ovf, 0, (size_t)n_atoms * sizeof(float), stream);
            pc_fused_bucket<<<NB, BLK_F, 0, stream>>>(
                qd, dist, idx_i, idx_j, slabs, counts, ovf,
                n_edges, n4, gps, CAP, NB);
            pc_scatter_bkt<<<BNCHUNK * S2, BLK_S, 0, stream>>>(
                slabs, counts, partial, NB, CAP, S2, n_atoms);
            pc_reduce_ovf<<<(n_atoms + 63) / 64, 256, 0, stream>>>(
                partial, ovf, out, n_atoms, S2);
            return;
        }
    }

    // ---- legacy multi-pass path ----
    size_t qd_bytes = ((size_t)n_atoms * sizeof(float2) + 255) & ~(size_t)255;
    size_t e_bytes  = ((size_t)n_edges * sizeof(float) + 255) & ~(size_t)255;
    size_t head     = qd_bytes + e_bytes;
    size_t avail    = (ws_size > head) ? ws_size - head : 0;
    int S = (int)(avail / ((size_t)n_atoms * sizeof(float)));
    if (S > S_FULL) S = S_FULL;
    S &= ~3;

    if (S >= 8 && n_atoms <= NCHUNK * CHUNK) {
        float2* qd      = (float2*)d_ws;
        float*  E       = (float*)((char*)d_ws + qd_bytes);
        float*  partial = (float*)((char*)d_ws + head);
        int     gps     = (n4 + S - 1) / S;

        pc_pack_qd<<<(n_atoms + 255) / 256, 256, 0, stream>>>(q, dip, qd,
                                                              n_atoms);
        int grid1 = (n4 + 255) / 256;
        if (grid1 < 1) grid1 = 1;
        pc_compute_E<<<grid1, 256, 0, stream>>>(qd, dist, idx_i, idx_j,
                                                E, n_edges, n4);
        pc_scatter<<<S * NCHUNK, BLOCK_SC, 0, stream>>>(
            idx_i, E, partial, n_edges, n4, S, gps, n_atoms);
        pc_reduce<<<(n_atoms + 63) / 64, 256, 0, stream>>>(partial, out,
                                                           n_atoms, S);
    } else {
        hipMemsetAsync(out, 0, (size_t)n_atoms * sizeof(float), stream);
        int grid = (n_edges + 255) / 256;
        pc_dipole_edges_atomic<<<grid, 256, 0, stream>>>(
            q, dip, dist, idx_i, idx_j, out, n_edges);
    }
}

// Round 6
// 200.443 us; speedup vs baseline: 1.1085x; 1.1085x over previous
//
#include <hip/hip_runtime.h>
#include <hip/hip_bf16.h>
#include <hip/hip_fp16.h>

// Problem constants (match reference)
#define CUTOFF_C    12.0f
#define CUTOFF_SR_C 2.0f
#define CUTOFF_SQ_C 144.0f
#define KEHALF_C    7.199822675975274f

// scatter configs
#define SH_BIG   15          // chunk 32768 floats = 128 KB dynamic LDS
#define NCH_BIG  4           // 4*32768 = 131072 >= 100000
#define S_BIG    64          // 64*4 = 256 blocks, 1/CU
#define BLK_BIG  1024

#define SH_SML   14          // chunk 16384 floats = 64 KB dynamic LDS
#define NCH_SML  7           // 7*16384 = 114688 >= 100000
#define S_SML    72          // 72*7 = 504 blocks, 2/CU
#define BLK_SML  512

__device__ __forceinline__ float edge_energy(float d, float qi, float qj,
                                             float di, float dj) {
    float inv_d   = __frcp_rn(d);
    float dsh     = __fsqrt_rn(fmaf(d, d, 1.0f));
    float inv_dsh = __frcp_rn(dsh);

    // poly6 switch on [0, CUTOFF_SR): 1 - 10x^3 + 15x^4 - 6x^5
    float x  = d * (1.0f / CUTOFF_SR_C);
    float x3 = x * x * x;
    float sw = fmaf(x3, fmaf(x, fmaf(x, -6.0f, 15.0f), -10.0f), 1.0f);
    float sw_off = (d < CUTOFF_SR_C) ? sw : 0.0f;

    float Eoq = inv_d   + fmaf(d,   (1.0f / CUTOFF_SQ_C), -(2.0f / CUTOFF_C));
    float Esq = inv_dsh + fmaf(dsh, (1.0f / CUTOFF_SQ_C), -(2.0f / CUTOFF_C));
    float Eq  = (KEHALF_C * qi * qj) * fmaf(sw_off, Esq - Eoq, Eoq);

    float Eod = inv_d * inv_d * inv_d;
    float Esd = inv_dsh * inv_dsh * inv_dsh;
    float Ed  = (KEHALF_C * di * dj) * fmaf(sw_off, Esd - Eod, Eod);

    return Eq + Ed;
}

// Pack {q, dip} -> __half2 (4 B): one dword gather per endpoint, 16 atoms
// per 64 B cache line.
__global__ __launch_bounds__(256) void pc_pack_qd_h(
    const float* __restrict__ q,
    const float* __restrict__ dip,
    __half2*     __restrict__ qd,
    int n_atoms)
{
    int a = blockIdx.x * 256 + threadIdx.x;
    if (a < n_atoms) qd[a] = __floats2half2_rn(q[a], dip[a]);
}

// Per-edge energy. KEY: all 8 gathers hoisted UNCONDITIONALLY before any
// compute, so each thread has 8 loads in flight (was 2 — the d<=cutoff
// branch serialized gather->use pairs). E written as fp16 (8 B per quad).
__global__ __launch_bounds__(256) void pc_compute_E_h(
    const __half2* __restrict__ qd,
    const float*   __restrict__ dist,
    const int*     __restrict__ idx_i,
    const int*     __restrict__ idx_j,
    __half*        __restrict__ E,
    int n_edges, int n4)
{
    int t = blockIdx.x * 256 + threadIdx.x;

    if (t < n4) {
        float4 d4 = ((const float4*)dist)[t];
        int4   i4 = ((const int4*)idx_i)[t];
        int4   j4 = ((const int4*)idx_j)[t];

        // ---- 8 independent gathers, all issued before first use ----
        __half2 hi0 = qd[i4.x];
        __half2 hj0 = qd[j4.x];
        __half2 hi1 = qd[i4.y];
        __half2 hj1 = qd[j4.y];
        __half2 hi2 = qd[i4.z];
        __half2 hj2 = qd[j4.z];
        __half2 hi3 = qd[i4.w];
        __half2 hj3 = qd[j4.w];

        float2 qi0 = __half22float2(hi0), qj0 = __half22float2(hj0);
        float2 qi1 = __half22float2(hi1), qj1 = __half22float2(hj1);
        float2 qi2 = __half22float2(hi2), qj2 = __half22float2(hj2);
        float2 qi3 = __half22float2(hi3), qj3 = __half22float2(hj3);

        float e0 = (d4.x <= CUTOFF_C)
                     ? edge_energy(d4.x, qi0.x, qj0.x, qi0.y, qj0.y) : 0.0f;
        float e1 = (d4.y <= CUTOFF_C)
                     ? edge_energy(d4.y, qi1.x, qj1.x, qi1.y, qj1.y) : 0.0f;
        float e2 = (d4.z <= CUTOFF_C)
                     ? edge_energy(d4.z, qi2.x, qj2.x, qi2.y, qj2.y) : 0.0f;
        float e3 = (d4.w <= CUTOFF_C)
                     ? edge_energy(d4.w, qi3.x, qj3.x, qi3.y, qj3.y) : 0.0f;

        union { uint2 u; __half2 h[2]; } pk;
        pk.h[0] = __floats2half2_rn(e0, e1);
        pk.h[1] = __floats2half2_rn(e2, e3);
        ((uint2*)E)[t] = pk.u;
    }

    // scalar tail (n_edges % 4)
    int total = gridDim.x * 256;
    for (int e = (n4 << 2) + t; e < n_edges; e += total) {
        float d = dist[e];
        float2 a = __half22float2(qd[idx_i[e]]);
        float2 b = __half22float2(qd[idx_j[e]]);
        float  v = (d <= CUTOFF_C) ? edge_energy(d, a.x, b.x, a.y, b.y) : 0.0f;
        E[e] = __float2half(v);
    }
}

// Multi-pass LDS filter-scatter, chunk = 1<<SHIFT floats of dynamic LDS.
// Block (s, c): stream slice s of (idx_i, E-fp16), ds_add atoms of chunk c,
// flush with plain coalesced stores into partial row s.
template <int SHIFT, int BLK, int NCH>
__global__ __launch_bounds__(BLK) void pc_scatter_h(
    const int*    __restrict__ idx_i,
    const __half* __restrict__ E,
    float*        __restrict__ partial,   // [S][n_atoms]
    int n_edges, int n4, int S, int gps, int n_atoms)
{
    extern __shared__ float acc[];
    const int CH = 1 << SHIFT;

    const int c    = blockIdx.x % NCH;
    const int s    = blockIdx.x / NCH;
    const int base = c << SHIFT;

    for (int i = threadIdx.x; i < CH; i += BLK) acc[i] = 0.0f;
    __syncthreads();

    const int g0 = s * gps;
    const int g1 = min(g0 + gps, n4);
    const int4*  idxi4 = (const int4*)idx_i;
    const uint2* E2p   = (const uint2*)E;

    for (int g = g0 + (int)threadIdx.x; g < g1; g += BLK) {
        int4  i4 = idxi4[g];
        uint2 eu = E2p[g];
        union { unsigned u; __half2 h; } ua, ub;
        ua.u = eu.x; ub.u = eu.y;
        float2 e01 = __half22float2(ua.h);
        float2 e23 = __half22float2(ub.h);

        unsigned l0 = (unsigned)(i4.x - base);
        unsigned l1 = (unsigned)(i4.y - base);
        unsigned l2 = (unsigned)(i4.z - base);
        unsigned l3 = (unsigned)(i4.w - base);
        if (l0 < (unsigned)CH && e01.x != 0.0f) atomicAdd(&acc[l0], e01.x);
        if (l1 < (unsigned)CH && e01.y != 0.0f) atomicAdd(&acc[l1], e01.y);
        if (l2 < (unsigned)CH && e23.x != 0.0f) atomicAdd(&acc[l2], e23.x);
        if (l3 < (unsigned)CH && e23.y != 0.0f) atomicAdd(&acc[l3], e23.y);
    }

    if (s == S - 1) {  // scalar tail
        for (int e = (n4 << 2) + (int)threadIdx.x; e < n_edges; e += BLK) {
            unsigned local = (unsigned)(idx_i[e] - base);
            float ev = __half2float(E[e]);
            if (local < (unsigned)CH && ev != 0.0f) atomicAdd(&acc[local], ev);
        }
    }

    __syncthreads();
    int lim = min(CH, n_atoms - base);
    float* row = partial + (size_t)s * n_atoms + base;
    for (int i = threadIdx.x; i < lim; i += BLK) row[i] = acc[i];
}

// out[a] = sum_s partial[s][a]; 4 waves/block, 64 atoms/block, LDS combine.
__global__ __launch_bounds__(256) void pc_reduce(
    const float* __restrict__ partial,
    float*       __restrict__ out,
    int n_atoms, int S)
{
    __shared__ float sh[256];
    int a0   = blockIdx.x * 64;
    int lane = threadIdx.x & 63;
    int w    = threadIdx.x >> 6;
    int a    = a0 + lane;

    float v0 = 0.0f, v1 = 0.0f;
    if (a < n_atoms) {
        int per = S >> 2;                 // S % 4 == 0
        const float* p = partial + a;
        int s = w * per, send = s + per;
        for (; s + 2 <= send; s += 2) {
            v0 += p[(size_t)(s + 0) * n_atoms];
            v1 += p[(size_t)(s + 1) * n_atoms];
        }
        for (; s < send; ++s) v0 += p[(size_t)s * n_atoms];
    }
    sh[threadIdx.x] = v0 + v1;
    __syncthreads();
    if (w == 0 && a < n_atoms)
        out[a] = (sh[lane] + sh[64 + lane]) + (sh[128 + lane] + sh[192 + lane]);
}

// Full fallback: global atomics on fp32 inputs (tiny ws).
__global__ __launch_bounds__(256) void pc_dipole_edges_atomic(
    const float* __restrict__ q,
    const float* __restrict__ dip,
    const float* __restrict__ dist,
    const int*   __restrict__ idx_i,
    const int*   __restrict__ idx_j,
    float*       __restrict__ out,
    int n_edges)
{
    int t = blockIdx.x * blockDim.x + threadIdx.x;
    const int stride = gridDim.x * blockDim.x;
    for (int e = t; e < n_edges; e += stride) {
        float d = dist[e];
        if (d > CUTOFF_C) continue;
        int i = idx_i[e], j = idx_j[e];
        atomicAdd(&out[i], edge_energy(d, q[i], q[j], dip[i], dip[j]));
    }
}

extern "C" void kernel_launch(void* const* d_in, const int* in_sizes, int n_in,
                              void* d_out, int out_size, void* d_ws, size_t ws_size,
                              hipStream_t stream) {
    const float* q     = (const float*)d_in[0];
    const float* dip   = (const float*)d_in[1];
    const float* dist  = (const float*)d_in[2];
    const int*   idx_i = (const int*)d_in[3];
    const int*   idx_j = (const int*)d_in[4];
    float*       out   = (float*)d_out;

    int n_edges = in_sizes[2];
    int n_atoms = out_size;
    int n4      = n_edges >> 2;

    // Can the big (128 KB dynamic LDS) scatter run on this device/runtime?
    // Capability probe every call (same work each call — capture-safe).
    bool big_ok = false;
    {
        hipError_t e1 = hipFuncSetAttribute(
            reinterpret_cast<const void*>(&pc_scatter_h<SH_BIG, BLK_BIG, NCH_BIG>),
            hipFuncAttributeMaxDynamicSharedMemorySize, 131072);
        int nb = 0;
        hipError_t e2 = hipOccupancyMaxActiveBlocksPerMultiprocessor(
            &nb, reinterpret_cast<const void*>(&pc_scatter_h<SH_BIG, BLK_BIG, NCH_BIG>),
            BLK_BIG, (size_t)131072);
        big_ok = (e1 == hipSuccess && e2 == hipSuccess && nb >= 1);
    }

    int S_target = big_ok ? S_BIG : S_SML;

    // Workspace: [qd: n_atoms half2][E: n_edges half][partial: S * n_atoms f32]
    size_t qd_b = ((size_t)n_atoms * sizeof(__half2) + 255) & ~(size_t)255;
    size_t e_b  = ((size_t)n_edges * sizeof(__half)  + 255) & ~(size_t)255;
    size_t head = qd_b + e_b;
    size_t avail = (ws_size > head) ? ws_size - head : 0;
    int S_fit = (int)(avail / ((size_t)n_atoms * sizeof(float)));

    int max_atoms = big_ok ? (NCH_BIG << SH_BIG) : (NCH_SML << SH_SML);

    if (S_fit >= 8 && n_atoms <= max_atoms && n_atoms > 0) {
        int S = (S_fit < S_target) ? (S_fit & ~3) : S_target;

        __half2* qd      = (__half2*)d_ws;
        __half*  E       = (__half*)((char*)d_ws + qd_b);
        float*   partial = (float*)((char*)d_ws + head);
        int      gps     = (n4 + S - 1) / S;

        pc_pack_qd_h<<<(n_atoms + 255) / 256, 256, 0, stream>>>(q, dip, qd,
                                                                n_atoms);
        int grid1 = (n4 + 255) / 256;
        if (grid1 < 1) grid1 = 1;
        pc_compute_E_h<<<grid1, 256, 0, stream>>>(qd, dist, idx_i, idx_j,
                                                  E, n_edges, n4);
        if (big_ok) {
            pc_scatter_h<SH_BIG, BLK_BIG, NCH_BIG>
                <<<S * NCH_BIG, BLK_BIG, 131072, stream>>>(
                    idx_i, E, partial, n_edges, n4, S, gps, n_atoms);
        } else {
            pc_scatter_h<SH_SML, BLK_SML, NCH_SML>
                <<<S * NCH_SML, BLK_SML, 65536, stream>>>(
                    idx_i, E, partial, n_edges, n4, S, gps, n_atoms);
        }
        pc_reduce<<<(n_atoms + 63) / 64, 256, 0, stream>>>(partial, out,
                                                           n_atoms, S);
    } else {
        hipMemsetAsync(out, 0, (size_t)n_atoms * sizeof(float), stream);
        int grid = (n_edges + 255) / 256;
        pc_dipole_edges_atomic<<<grid, 256, 0, stream>>>(
            q, dip, dist, idx_i, idx_j, out, n_edges);
    }
}